// Round 2
// baseline (358.287 us; speedup 1.0000x reference)
//
#include <hip/hip_runtime.h>

#define BTOT 32768
#define FDIM 128
#define TDIM 32
#define DDIM 16
#define HDIM 10
#define ALPHA_C 0.1f
#define MARGIN_C 1.0f
#define SLOPE_C 0.2f
#define OFFSET_C 1.0e6f

// ws float offsets
#define WS_A0 0            // 32*128*10 = 40960 floats
#define WS_MEAN 40960      // 320 floats
#define WS_TC 41280        // 1 float (+pad to 41344)
#define WS_CE 41344        // 32768 floats

__device__ __forceinline__ float leaky(float x) { return x >= 0.f ? x : SLOPE_C * x; }

// A0[t,n,o] = sum_d aw[t,n,d] * W0[o,d]
__global__ void prep_kernel(const float* __restrict__ aw, const float* __restrict__ W0,
                            float* __restrict__ A0) {
    int idx = blockIdx.x * blockDim.x + threadIdx.x;   // t*F + n, 4096 total
    if (idx >= TDIM * FDIM) return;
    const float* a = aw + (size_t)idx * DDIM;
    float* dst = A0 + (size_t)idx * HDIM;
#pragma unroll
    for (int o = 0; o < HDIM; ++o) {
        float s = 0.f;
#pragma unroll
        for (int d = 0; d < DDIM; ++d) s += a[d] * W0[o * DDIM + d];
        dst[o] = s;
    }
}

// 512 threads = 8 waves. Block covers 64 b's (one per lane). Wave w handles t in [4w, 4w+4).
// Writes batch_rep, per-b mean CE, and atomically accumulates class-mean sums.
__global__ __launch_bounds__(512) void phase1_kernel(
    const float* __restrict__ X, const float* __restrict__ A0,
    const float* __restrict__ W1, const float* __restrict__ W2,
    const float* __restrict__ W3, const float* __restrict__ Wh,
    const float* __restrict__ bh,
    float* __restrict__ out_rep, float* __restrict__ ce_mean,
    float* __restrict__ mean_acc)
{
    __shared__ float xs[64][129];   // +1 pad: lanes hit distinct banks (2-way = free)
    __shared__ float ce_part[8][64];
    int tid = threadIdx.x;
    int b0 = blockIdx.x * 64;

    // coalesced X stage: 64 rows x 128 cols (512 threads x 4 float4s... 2048 float4 total)
    for (int i = tid; i < 64 * FDIM / 4; i += 512) {
        float4 v = reinterpret_cast<const float4*>(X + (size_t)b0 * FDIM)[i];
        int row = i >> 5;
        int col = (i & 31) * 4;
        xs[row][col + 0] = v.x; xs[row][col + 1] = v.y;
        xs[row][col + 2] = v.z; xs[row][col + 3] = v.w;
    }
    __syncthreads();

    int lane = tid & 63;
    int w = __builtin_amdgcn_readfirstlane(tid >> 6);   // wave-uniform t-group

    // ---- first layer, t-blocked: 4 t's share each LDS read ----
    float acc[4][HDIM];
#pragma unroll
    for (int tt = 0; tt < 4; ++tt)
#pragma unroll
        for (int o = 0; o < HDIM; ++o) acc[tt][o] = 0.f;

    const float* a0base = A0 + (size_t)(4 * w) * FDIM * HDIM;
    for (int n = 0; n < FDIM; ++n) {
        float xv = xs[lane][n];
#pragma unroll
        for (int tt = 0; tt < 4; ++tt) {
            const float* ar = a0base + ((size_t)tt * FDIM + n) * HDIM;
#pragma unroll
            for (int o = 0; o < HDIM; ++o) acc[tt][o] += xv * ar[o];
        }
    }

    float ce_sum = 0.f;
#pragma unroll
    for (int tt = 0; tt < 4; ++tt) {
        int t = 4 * w + tt;
        float g[HDIM], lh[HDIM];
#pragma unroll
        for (int o = 0; o < HDIM; ++o) lh[o] = leaky(acc[tt][o]);
#pragma unroll
        for (int o = 0; o < HDIM; ++o) { float s = 0.f;
#pragma unroll
            for (int j = 0; j < HDIM; ++j) s += W1[o * HDIM + j] * lh[j]; g[o] = s; }
#pragma unroll
        for (int o = 0; o < HDIM; ++o) lh[o] = leaky(g[o]);
#pragma unroll
        for (int o = 0; o < HDIM; ++o) { float s = 0.f;
#pragma unroll
            for (int j = 0; j < HDIM; ++j) s += W2[o * HDIM + j] * lh[j]; g[o] = s; }
#pragma unroll
        for (int o = 0; o < HDIM; ++o) lh[o] = leaky(g[o]);
#pragma unroll
        for (int o = 0; o < HDIM; ++o) { float s = 0.f;
#pragma unroll
            for (int j = 0; j < HDIM; ++j) s += W3[o * HDIM + j] * lh[j]; g[o] = s; }

        // g = rep[b, t, :]
        float* orp = out_rep + ((size_t)(b0 + lane) * TDIM + t) * HDIM;
#pragma unroll
        for (int o = 0; o < HDIM; ++o) orp[o] = g[o];

        // class-mean partial: reduce g over the wave's 64 b's, lane 0 atomics
#pragma unroll
        for (int o = 0; o < HDIM; ++o) {
            float v = g[o];
#pragma unroll
            for (int m = 1; m < 64; m <<= 1) v += __shfl_xor(v, m, 64);
            if (lane == 0) atomicAdd(&mean_acc[t * HDIM + o], v);
        }

        // head + CE(class=t)
#pragma unroll
        for (int o = 0; o < HDIM; ++o) lh[o] = leaky(g[o]);
        float p[TDIM];
        float mx = -1e30f;
#pragma unroll
        for (int o = 0; o < TDIM; ++o) {
            float s = bh[o];
#pragma unroll
            for (int j = 0; j < HDIM; ++j) s += Wh[o * HDIM + j] * lh[j];
            p[o] = s; mx = fmaxf(mx, s);
        }
        float se = 0.f, pt = 0.f;
#pragma unroll
        for (int o = 0; o < TDIM; ++o) { se += __expf(p[o] - mx); if (o == t) pt = p[o]; }
        ce_sum += (mx + __logf(se) - pt);
    }

    ce_part[w][lane] = ce_sum;
    __syncthreads();
    if (tid < 64) {
        float s = 0.f;
#pragma unroll
        for (int ww = 0; ww < 8; ++ww) s += ce_part[ww][tid];
        ce_mean[b0 + tid] = s * (1.f / TDIM);
    }
}

// triplet-center hinge: 1 thread per (b,t)
__global__ __launch_bounds__(256) void tc_kernel(const float* __restrict__ rep,
    const float* __restrict__ mean_acc, float* __restrict__ tc_sum)
{
    __shared__ float mm[TDIM * HDIM];
    __shared__ float wpart[4];
    int tid = threadIdx.x;
    for (int i = tid; i < TDIM * HDIM; i += 256) mm[i] = mean_acc[i] * (1.f / BTOT);
    __syncthreads();
    size_t idx = (size_t)blockIdx.x * 256 + tid;   // b*32 + t
    int t = (int)(idx & 31);
    const float* r = rep + idx * HDIM;
    float rv[HDIM];
#pragma unroll
    for (int h = 0; h < HDIM; ++h) rv[h] = r[h];
    float pos = 0.f, neg = 1e30f;
#pragma unroll
    for (int c = 0; c < TDIM; ++c) {
        float s = 0.f;
#pragma unroll
        for (int h = 0; h < HDIM; ++h) { float d = rv[h] - mm[c * HDIM + h]; s += d * d; }
        if (c == t) pos = s;
        float s2 = (c == t) ? s + OFFSET_C : s;
        neg = fminf(neg, s2);
    }
    float hinge = fmaxf(pos + MARGIN_C - neg, 0.f);
#pragma unroll
    for (int m = 32; m; m >>= 1) hinge += __shfl_xor(hinge, m, 64);
    int lane = tid & 63, wid = tid >> 6;
    if (lane == 0) wpart[wid] = hinge;
    __syncthreads();
    if (tid == 0) atomicAdd(tc_sum, wpart[0] + wpart[1] + wpart[2] + wpart[3]);
}

__global__ void final_kernel(const float* __restrict__ ce_mean,
                             const float* __restrict__ tc_sum, float* __restrict__ loss)
{
    int b = blockIdx.x * blockDim.x + threadIdx.x;
    if (b < BTOT)
        loss[b] = ALPHA_C * (tc_sum[0] * (1.f / ((float)BTOT * TDIM))) + ce_mean[b];
}

extern "C" void kernel_launch(void* const* d_in, const int* in_sizes, int n_in,
                              void* d_out, int out_size, void* d_ws, size_t ws_size,
                              hipStream_t stream) {
    const float* X  = (const float*)d_in[0];
    const float* aw = (const float*)d_in[1];
    const float* W0 = (const float*)d_in[2];
    const float* W1 = (const float*)d_in[3];
    const float* W2 = (const float*)d_in[4];
    const float* W3 = (const float*)d_in[5];
    const float* Wh = (const float*)d_in[6];
    const float* bh = (const float*)d_in[7];
    float* ws = (float*)d_ws;
    float* A0       = ws + WS_A0;
    float* mean_acc = ws + WS_MEAN;
    float* tc_sum   = ws + WS_TC;
    float* ce_mean  = ws + WS_CE;
    float* out_rep = (float*)d_out;
    float* loss = out_rep + (size_t)BTOT * TDIM * HDIM;

    // zero mean_acc + tc_sum (384 floats); capture-safe async memset
    hipMemsetAsync(mean_acc, 0, 384 * sizeof(float), stream);
    prep_kernel<<<16, 256, 0, stream>>>(aw, W0, A0);
    phase1_kernel<<<512, 512, 0, stream>>>(X, A0, W1, W2, W3, Wh, bh,
                                           out_rep, ce_mean, mean_acc);
    tc_kernel<<<(BTOT * TDIM) / 256, 256, 0, stream>>>(out_rep, mean_acc, tc_sum);
    final_kernel<<<BTOT / 256, 256, 0, stream>>>(ce_mean, tc_sum, loss);
}

// Round 3
// 189.438 us; speedup vs baseline: 1.8913x; 1.8913x over previous
//
#include <hip/hip_runtime.h>

#define BTOT 32768
#define FDIM 128
#define TDIM 32
#define DDIM 16
#define HDIM 10
#define ALPHA_C 0.1f
#define MARGIN_C 1.0f
#define SLOPE_C 0.2f
#define OFFSET_C 1.0e6f

// ws float offsets
#define WS_A0 0            // 32*128*10 = 40960 floats
#define WS_MEAN 40960      // 320 floats
#define WS_TC 41280        // 1 float (+pad to 41344)
#define WS_CE 41344        // 32768 floats

__device__ __forceinline__ float leaky(float x) { return x >= 0.f ? x : SLOPE_C * x; }

// A0[t,n,o] = sum_d aw[t,n,d] * W0[o,d]
__global__ void prep_kernel(const float* __restrict__ aw, const float* __restrict__ W0,
                            float* __restrict__ A0) {
    int idx = blockIdx.x * blockDim.x + threadIdx.x;   // t*F + n, 4096 total
    if (idx >= TDIM * FDIM) return;
    const float* a = aw + (size_t)idx * DDIM;
    float* dst = A0 + (size_t)idx * HDIM;
#pragma unroll
    for (int o = 0; o < HDIM; ++o) {
        float s = 0.f;
#pragma unroll
        for (int d = 0; d < DDIM; ++d) s += a[d] * W0[o * DDIM + d];
        dst[o] = s;
    }
}

// 512 threads = 8 waves. Block covers 64 b's (one per lane). Wave w handles t in [4w, 4w+4).
// NO cross-lane ops, NO atomics in the hot loop: keeps the scalar-load (A0/W) prefetch
// pipeline intact (lgkmcnt is shared between LDS-ops and SMEM loads — shuffles drain it).
__global__ __launch_bounds__(512) void phase1_kernel(
    const float* __restrict__ X, const float* __restrict__ A0,
    const float* __restrict__ W1, const float* __restrict__ W2,
    const float* __restrict__ W3, const float* __restrict__ Wh,
    const float* __restrict__ bh,
    float* __restrict__ out_rep, float* __restrict__ ce_mean)
{
    __shared__ float xs[64][129];   // +1 pad: 2-way bank conflict (free)
    __shared__ float ce_part[8][64];
    int tid = threadIdx.x;
    int b0 = blockIdx.x * 64;

    // coalesced X stage: 64 rows x 128 cols
    for (int i = tid; i < 64 * FDIM / 4; i += 512) {
        float4 v = reinterpret_cast<const float4*>(X + (size_t)b0 * FDIM)[i];
        int row = i >> 5;
        int col = (i & 31) * 4;
        xs[row][col + 0] = v.x; xs[row][col + 1] = v.y;
        xs[row][col + 2] = v.z; xs[row][col + 3] = v.w;
    }
    __syncthreads();

    int lane = tid & 63;
    int w = __builtin_amdgcn_readfirstlane(tid >> 6);   // wave-uniform t-group

    // ---- first layer, t-blocked: 4 t's share each LDS read ----
    float acc[4][HDIM];
#pragma unroll
    for (int tt = 0; tt < 4; ++tt)
#pragma unroll
        for (int o = 0; o < HDIM; ++o) acc[tt][o] = 0.f;

    const float* a0base = A0 + (size_t)(4 * w) * FDIM * HDIM;
    for (int n = 0; n < FDIM; ++n) {
        float xv = xs[lane][n];
#pragma unroll
        for (int tt = 0; tt < 4; ++tt) {
            const float* ar = a0base + ((size_t)tt * FDIM + n) * HDIM;
#pragma unroll
            for (int o = 0; o < HDIM; ++o) acc[tt][o] += xv * ar[o];
        }
    }

    float ce_sum = 0.f;
#pragma unroll
    for (int tt = 0; tt < 4; ++tt) {
        int t = 4 * w + tt;
        float g[HDIM], lh[HDIM];
#pragma unroll
        for (int o = 0; o < HDIM; ++o) lh[o] = leaky(acc[tt][o]);
#pragma unroll
        for (int o = 0; o < HDIM; ++o) { float s = 0.f;
#pragma unroll
            for (int j = 0; j < HDIM; ++j) s += W1[o * HDIM + j] * lh[j]; g[o] = s; }
#pragma unroll
        for (int o = 0; o < HDIM; ++o) lh[o] = leaky(g[o]);
#pragma unroll
        for (int o = 0; o < HDIM; ++o) { float s = 0.f;
#pragma unroll
            for (int j = 0; j < HDIM; ++j) s += W2[o * HDIM + j] * lh[j]; g[o] = s; }
#pragma unroll
        for (int o = 0; o < HDIM; ++o) lh[o] = leaky(g[o]);
#pragma unroll
        for (int o = 0; o < HDIM; ++o) { float s = 0.f;
#pragma unroll
            for (int j = 0; j < HDIM; ++j) s += W3[o * HDIM + j] * lh[j]; g[o] = s; }

        // g = rep[b, t, :]
        float* orp = out_rep + ((size_t)(b0 + lane) * TDIM + t) * HDIM;
#pragma unroll
        for (int o = 0; o < HDIM; ++o) orp[o] = g[o];

        // head + CE(class=t)
#pragma unroll
        for (int o = 0; o < HDIM; ++o) lh[o] = leaky(g[o]);
        float p[TDIM];
        float mx = -1e30f;
#pragma unroll
        for (int o = 0; o < TDIM; ++o) {
            float s = bh[o];
#pragma unroll
            for (int j = 0; j < HDIM; ++j) s += Wh[o * HDIM + j] * lh[j];
            p[o] = s; mx = fmaxf(mx, s);
        }
        float se = 0.f, pt = 0.f;
#pragma unroll
        for (int o = 0; o < TDIM; ++o) { se += __expf(p[o] - mx); if (o == t) pt = p[o]; }
        ce_sum += (mx + __logf(se) - pt);
    }

    ce_part[w][lane] = ce_sum;
    __syncthreads();
    if (tid < 64) {
        float s = 0.f;
#pragma unroll
        for (int ww = 0; ww < 8; ++ww) s += ce_part[ww][tid];
        ce_mean[b0 + tid] = s * (1.f / TDIM);
    }
}

// mean accumulation: block = 320 threads (one per (t,h)), 128 b's per block, coalesced
__global__ void meanred_kernel(const float* __restrict__ rep, float* __restrict__ mean_acc)
{
    int j = threadIdx.x;                   // 0..319
    const float* base = rep + (size_t)blockIdx.x * 128 * (TDIM * HDIM);
    float s0 = 0, s1 = 0, s2 = 0, s3 = 0;
    for (int b = 0; b < 128; b += 4) {
        s0 += base[(size_t)(b + 0) * 320 + j];
        s1 += base[(size_t)(b + 1) * 320 + j];
        s2 += base[(size_t)(b + 2) * 320 + j];
        s3 += base[(size_t)(b + 3) * 320 + j];
    }
    atomicAdd(&mean_acc[j], s0 + s1 + s2 + s3);
}

// triplet-center hinge: 1 thread per (b,t)
__global__ __launch_bounds__(256) void tc_kernel(const float* __restrict__ rep,
    const float* __restrict__ mean_acc, float* __restrict__ tc_sum)
{
    __shared__ float mm[TDIM * HDIM];
    __shared__ float wpart[4];
    int tid = threadIdx.x;
    for (int i = tid; i < TDIM * HDIM; i += 256) mm[i] = mean_acc[i] * (1.f / BTOT);
    __syncthreads();
    size_t idx = (size_t)blockIdx.x * 256 + tid;   // b*32 + t
    int t = (int)(idx & 31);
    const float* r = rep + idx * HDIM;
    float rv[HDIM];
#pragma unroll
    for (int h = 0; h < HDIM; ++h) rv[h] = r[h];
    float pos = 0.f, neg = 1e30f;
#pragma unroll
    for (int c = 0; c < TDIM; ++c) {
        float s = 0.f;
#pragma unroll
        for (int h = 0; h < HDIM; ++h) { float d = rv[h] - mm[c * HDIM + h]; s += d * d; }
        if (c == t) pos = s;
        float s2 = (c == t) ? s + OFFSET_C : s;
        neg = fminf(neg, s2);
    }
    float hinge = fmaxf(pos + MARGIN_C - neg, 0.f);
#pragma unroll
    for (int m = 32; m; m >>= 1) hinge += __shfl_xor(hinge, m, 64);
    int lane = tid & 63, wid = tid >> 6;
    if (lane == 0) wpart[wid] = hinge;
    __syncthreads();
    if (tid == 0) atomicAdd(tc_sum, wpart[0] + wpart[1] + wpart[2] + wpart[3]);
}

__global__ void final_kernel(const float* __restrict__ ce_mean,
                             const float* __restrict__ tc_sum, float* __restrict__ loss)
{
    int b = blockIdx.x * blockDim.x + threadIdx.x;
    if (b < BTOT)
        loss[b] = ALPHA_C * (tc_sum[0] * (1.f / ((float)BTOT * TDIM))) + ce_mean[b];
}

extern "C" void kernel_launch(void* const* d_in, const int* in_sizes, int n_in,
                              void* d_out, int out_size, void* d_ws, size_t ws_size,
                              hipStream_t stream) {
    const float* X  = (const float*)d_in[0];
    const float* aw = (const float*)d_in[1];
    const float* W0 = (const float*)d_in[2];
    const float* W1 = (const float*)d_in[3];
    const float* W2 = (const float*)d_in[4];
    const float* W3 = (const float*)d_in[5];
    const float* Wh = (const float*)d_in[6];
    const float* bh = (const float*)d_in[7];
    float* ws = (float*)d_ws;
    float* A0       = ws + WS_A0;
    float* mean_acc = ws + WS_MEAN;
    float* tc_sum   = ws + WS_TC;
    float* ce_mean  = ws + WS_CE;
    float* out_rep = (float*)d_out;
    float* loss = out_rep + (size_t)BTOT * TDIM * HDIM;

    // zero mean_acc + tc_sum (384 floats); capture-safe async memset
    hipMemsetAsync(mean_acc, 0, 384 * sizeof(float), stream);
    prep_kernel<<<16, 256, 0, stream>>>(aw, W0, A0);
    phase1_kernel<<<512, 512, 0, stream>>>(X, A0, W1, W2, W3, Wh, bh,
                                           out_rep, ce_mean);
    meanred_kernel<<<256, 320, 0, stream>>>(out_rep, mean_acc);
    tc_kernel<<<(BTOT * TDIM) / 256, 256, 0, stream>>>(out_rep, mean_acc, tc_sum);
    final_kernel<<<BTOT / 256, 256, 0, stream>>>(ce_mean, tc_sum, loss);
}

// Round 4
// 169.077 us; speedup vs baseline: 2.1191x; 1.1204x over previous
//
#include <hip/hip_runtime.h>

typedef __attribute__((ext_vector_type(8))) short bf16x8;
typedef __attribute__((ext_vector_type(4))) float f32x4;

#define BTOT 32768
#define FDIM 128
#define TDIM 32
#define DDIM 16
#define HDIM 10
#define CDIM 320            // T*H
#define ALPHA_C 0.1f
#define MARGIN_C 1.0f
#define SLOPE_C 0.2f
#define OFFSET_C 1.0e6f

// ws float offsets
#define WS_A0BF 0           // 320*128 bf16 = 20480 floats of storage
#define WS_MEAN 20480       // 320 floats
#define WS_TC   20800       // 1 float (pad to 20864)
#define WS_CE   20864       // 32768 floats (written, not accumulated)

__device__ __forceinline__ float leaky(float x) { return x >= 0.f ? x : SLOPE_C * x; }

__device__ __forceinline__ unsigned short f2bf(float f) {   // RNE f32->bf16
    unsigned int u = __float_as_uint(f);
    u += 0x7fffu + ((u >> 16) & 1u);
    return (unsigned short)(u >> 16);
}

// A0bf[c][n] (bf16, c-major), c = t*10+o:  sum_d aw[t,n,d] * W0[o,d]
__global__ void prep_kernel(const float* __restrict__ aw, const float* __restrict__ W0,
                            unsigned short* __restrict__ a0bf) {
    int idx = blockIdx.x * blockDim.x + threadIdx.x;   // c*128 + n
    if (idx >= CDIM * FDIM) return;
    int c = idx >> 7, n = idx & 127;
    int t = c / HDIM, o = c - t * HDIM;
    const float* a = aw + ((size_t)t * FDIM + n) * DDIM;
    const float* w = W0 + o * DDIM;
    float s = 0.f;
#pragma unroll
    for (int d = 0; d < DDIM; ++d) s += a[d] * w[d];
    a0bf[idx] = f2bf(s);
}

// GEMM layer0: Y[b, c] = sum_n X[b,n]*A0[n,c], bf16 MFMA 16x16x32.
// Block: 256 thr = 4 waves; tile 64 b x 80 c; wave w owns b-subtile w, all 5 c-tiles.
// Y written INTO the rep output buffer (same slots the down_kernel later overwrites).
__global__ __launch_bounds__(256) void gemm0_kernel(
    const float* __restrict__ X, const unsigned short* __restrict__ a0bf,
    float* __restrict__ Y)
{
    __shared__ unsigned short xs[64][136];   // +8 pad: frag b128 reads 2-way (free)
    __shared__ unsigned short a0s[80][136];
    __shared__ float ys[64][84];             // 84: 16B-aligned rows, conflict-free D writes
    int tid = threadIdx.x;
    int bchunk = blockIdx.x >> 2, cchunk = blockIdx.x & 3;
    int b0 = bchunk * 64, c0 = cchunk * 80;

    // stage X tile (f32 -> bf16), coalesced float4
#pragma unroll
    for (int k = 0; k < 8; ++k) {
        int idx = tid + k * 256;             // 2048 float4
        int row = idx >> 5, col4 = idx & 31;
        float4 v = reinterpret_cast<const float4*>(X + (size_t)(b0 + row) * FDIM)[col4];
        uint2 pk;
        pk.x = (unsigned)f2bf(v.x) | ((unsigned)f2bf(v.y) << 16);
        pk.y = (unsigned)f2bf(v.z) | ((unsigned)f2bf(v.w) << 16);
        *reinterpret_cast<uint2*>(&xs[row][col4 * 4]) = pk;
    }
    // stage A0 tile (80 rows x 256 B, contiguous), coalesced uint4
#pragma unroll
    for (int k = 0; k < 5; ++k) {
        int idx = tid + k * 256;             // 1280 uint4
        int row = idx >> 4, j = idx & 15;
        uint4 v = reinterpret_cast<const uint4*>(a0bf + (size_t)(c0 + row) * FDIM)[j];
        *reinterpret_cast<uint4*>(&a0s[row][j * 8]) = v;
    }
    __syncthreads();

    int lane = tid & 63, w = tid >> 6;
    int r16 = lane & 15, g = lane >> 4;
    // A-frags: lane holds X[wb*16 + r16, k], k = s*32 + g*8 + [0..8)
    bf16x8 af[4];
#pragma unroll
    for (int s = 0; s < 4; ++s)
        af[s] = *reinterpret_cast<const bf16x8*>(&xs[w * 16 + r16][s * 32 + g * 8]);
#pragma unroll
    for (int ct = 0; ct < 5; ++ct) {
        f32x4 acc = {0.f, 0.f, 0.f, 0.f};
#pragma unroll
        for (int s = 0; s < 4; ++s) {
            // B-frag: same k-mapping as A (permutation-safe), col = r16
            bf16x8 bfrag = *reinterpret_cast<const bf16x8*>(&a0s[ct * 16 + r16][s * 32 + g * 8]);
            acc = __builtin_amdgcn_mfma_f32_16x16x32_bf16(af[s], bfrag, acc, 0, 0, 0);
        }
        // D: row = g*4 + r (within wave's 16), col = r16  [HW-verified layout]
#pragma unroll
        for (int r = 0; r < 4; ++r)
            ys[w * 16 + g * 4 + r][ct * 16 + r16] = acc[r];
    }
    __syncthreads();

    // coalesced copy ys -> Y (f32): 64 rows x 80 f32 = 1280 float4
#pragma unroll
    for (int k = 0; k < 5; ++k) {
        int idx = tid + k * 256;
        int row = idx / 20, j = idx - row * 20;
        float4 v = *reinterpret_cast<const float4*>(&ys[row][j * 4]);
        reinterpret_cast<float4*>(Y + (size_t)(b0 + row) * CDIM + c0)[j] = v;
    }
}

// Downstream: per (b,t): read Y (own slot), W1..W3 chain, head+CE, write rep in place.
// Block 256 thr covers 32 b x 32 t; thread: t = tid&31, 4 b's. No big LDS -> high occupancy.
__global__ __launch_bounds__(256) void down_kernel(
    float* __restrict__ YR,              // in: layer0 out; out: rep (same slots)
    const float* __restrict__ W1, const float* __restrict__ W2,
    const float* __restrict__ W3, const float* __restrict__ Wh,
    const float* __restrict__ bh,
    float* __restrict__ ce_mean, float* __restrict__ mean_acc)
{
    __shared__ float mred[8][TDIM][HDIM];   // 10 KB
    int tid = threadIdx.x;
    int t = tid & 31, gq = tid >> 5;        // gq in [0,8)
    int b0 = blockIdx.x * 32;
    float msum[HDIM];
#pragma unroll
    for (int o = 0; o < HDIM; ++o) msum[o] = 0.f;
    float ce[4];

#pragma unroll
    for (int j = 0; j < 4; ++j) {
        int b = b0 + gq * 4 + j;
        float* yp = YR + (size_t)b * CDIM + t * HDIM;
        float h[HDIM], lh[HDIM], gg[HDIM];
        // load 10 f32 (8B-aligned float2 x5)
#pragma unroll
        for (int q = 0; q < 5; ++q) {
            float2 v = reinterpret_cast<const float2*>(yp)[q];
            h[2 * q] = v.x; h[2 * q + 1] = v.y;
        }
#pragma unroll
        for (int o = 0; o < HDIM; ++o) lh[o] = leaky(h[o]);
#pragma unroll
        for (int o = 0; o < HDIM; ++o) { float s = 0.f;
#pragma unroll
            for (int i = 0; i < HDIM; ++i) s += W1[o * HDIM + i] * lh[i]; gg[o] = s; }
#pragma unroll
        for (int o = 0; o < HDIM; ++o) lh[o] = leaky(gg[o]);
#pragma unroll
        for (int o = 0; o < HDIM; ++o) { float s = 0.f;
#pragma unroll
            for (int i = 0; i < HDIM; ++i) s += W2[o * HDIM + i] * lh[i]; h[o] = s; }
#pragma unroll
        for (int o = 0; o < HDIM; ++o) lh[o] = leaky(h[o]);
#pragma unroll
        for (int o = 0; o < HDIM; ++o) { float s = 0.f;
#pragma unroll
            for (int i = 0; i < HDIM; ++i) s += W3[o * HDIM + i] * lh[i]; gg[o] = s; }

        // rep write (same slot), means partial
#pragma unroll
        for (int q = 0; q < 5; ++q) {
            float2 v; v.x = gg[2 * q]; v.y = gg[2 * q + 1];
            reinterpret_cast<float2*>(yp)[q] = v;
        }
#pragma unroll
        for (int o = 0; o < HDIM; ++o) msum[o] += gg[o];

        // head + CE(class = t)
#pragma unroll
        for (int o = 0; o < HDIM; ++o) lh[o] = leaky(gg[o]);
        float mx = -1e30f, p[TDIM];
#pragma unroll
        for (int o = 0; o < TDIM; ++o) {
            float s = bh[o];
#pragma unroll
            for (int i = 0; i < HDIM; ++i) s += Wh[o * HDIM + i] * lh[i];
            p[o] = s; mx = fmaxf(mx, s);
        }
        float se = 0.f, pt = 0.f;
#pragma unroll
        for (int o = 0; o < TDIM; ++o) { se += __expf(p[o] - mx); if (o == t) pt = p[o]; }
        ce[j] = mx + __logf(se) - pt;
    }

    // CE: reduce over the 32 lanes sharing b (same half-wave), lane (tid&31)==0 writes
#pragma unroll
    for (int j = 0; j < 4; ++j) {
        float s = ce[j];
#pragma unroll
        for (int m = 1; m < 32; m <<= 1) s += __shfl_xor(s, m, 64);
        if ((tid & 31) == 0) ce_mean[b0 + gq * 4 + j] = s * (1.f / TDIM);
    }
    // means: block tree then one atomic per (t,o)
#pragma unroll
    for (int o = 0; o < HDIM; ++o) mred[gq][t][o] = msum[o];
    __syncthreads();
    for (int i = tid; i < TDIM * HDIM; i += 256) {
        int tt = i / HDIM, oo = i - tt * HDIM;
        float s = 0.f;
#pragma unroll
        for (int g2 = 0; g2 < 8; ++g2) s += mred[g2][tt][oo];
        atomicAdd(&mean_acc[i], s);
    }
}

// triplet-center hinge: 1 thread per (b,t)
__global__ __launch_bounds__(256) void tc_kernel(const float* __restrict__ rep,
    const float* __restrict__ mean_acc, float* __restrict__ tc_sum)
{
    __shared__ float mm[TDIM * HDIM];
    __shared__ float wpart[4];
    int tid = threadIdx.x;
    for (int i = tid; i < TDIM * HDIM; i += 256) mm[i] = mean_acc[i] * (1.f / BTOT);
    __syncthreads();
    size_t idx = (size_t)blockIdx.x * 256 + tid;   // b*32 + t
    int t = (int)(idx & 31);
    const float* r = rep + idx * HDIM;
    float rv[HDIM];
#pragma unroll
    for (int h = 0; h < HDIM; ++h) rv[h] = r[h];
    float pos = 0.f, neg = 1e30f;
#pragma unroll
    for (int c = 0; c < TDIM; ++c) {
        float s = 0.f;
#pragma unroll
        for (int h = 0; h < HDIM; ++h) { float d = rv[h] - mm[c * HDIM + h]; s += d * d; }
        if (c == t) pos = s;
        float s2 = (c == t) ? s + OFFSET_C : s;
        neg = fminf(neg, s2);
    }
    float hinge = fmaxf(pos + MARGIN_C - neg, 0.f);
#pragma unroll
    for (int m = 32; m; m >>= 1) hinge += __shfl_xor(hinge, m, 64);
    int lane = tid & 63, wid = tid >> 6;
    if (lane == 0) wpart[wid] = hinge;
    __syncthreads();
    if (tid == 0) atomicAdd(tc_sum, wpart[0] + wpart[1] + wpart[2] + wpart[3]);
}

__global__ void final_kernel(const float* __restrict__ ce_mean,
                             const float* __restrict__ tc_sum, float* __restrict__ loss)
{
    int b = blockIdx.x * blockDim.x + threadIdx.x;
    if (b < BTOT)
        loss[b] = ALPHA_C * (tc_sum[0] * (1.f / ((float)BTOT * TDIM))) + ce_mean[b];
}

extern "C" void kernel_launch(void* const* d_in, const int* in_sizes, int n_in,
                              void* d_out, int out_size, void* d_ws, size_t ws_size,
                              hipStream_t stream) {
    const float* X  = (const float*)d_in[0];
    const float* aw = (const float*)d_in[1];
    const float* W0 = (const float*)d_in[2];
    const float* W1 = (const float*)d_in[3];
    const float* W2 = (const float*)d_in[4];
    const float* W3 = (const float*)d_in[5];
    const float* Wh = (const float*)d_in[6];
    const float* bh = (const float*)d_in[7];
    float* ws = (float*)d_ws;
    unsigned short* a0bf = (unsigned short*)(ws + WS_A0BF);
    float* mean_acc = ws + WS_MEAN;
    float* tc_sum   = ws + WS_TC;
    float* ce_mean  = ws + WS_CE;
    float* out_rep = (float*)d_out;        // [32768][320]; gemm0 stages Y here in place
    float* loss = out_rep + (size_t)BTOT * TDIM * HDIM;

    hipMemsetAsync(mean_acc, 0, 384 * sizeof(float), stream);
    prep_kernel<<<(CDIM * FDIM) / 256, 256, 0, stream>>>(aw, W0, a0bf);
    gemm0_kernel<<<2048, 256, 0, stream>>>(X, a0bf, out_rep);
    down_kernel<<<BTOT / 32, 256, 0, stream>>>(out_rep, W1, W2, W3, Wh, bh,
                                               ce_mean, mean_acc);
    tc_kernel<<<(BTOT * TDIM) / 256, 256, 0, stream>>>(out_rep, mean_acc, tc_sum);
    final_kernel<<<BTOT / 256, 256, 0, stream>>>(ce_mean, tc_sum, loss);
}

// Round 5
// 123.792 us; speedup vs baseline: 2.8943x; 1.3658x over previous
//
#include <hip/hip_runtime.h>

typedef __attribute__((ext_vector_type(8))) short bf16x8;
typedef __attribute__((ext_vector_type(4))) float f32x4;

#define BTOT 32768
#define FDIM 128
#define TDIM 32
#define DDIM 16
#define HDIM 10
#define CDIM 320            // T*H
#define ALPHA_C 0.1f
#define MARGIN_C 1.0f
#define SLOPE_C 0.2f
#define OFFSET_C 1.0e6f

// ws float offsets
#define WS_A0BF 0           // 320*128 bf16 = 20480 floats of storage
#define WS_MEAN 20480       // 320 floats
#define WS_TC   20800       // 1 float (pad to 20864)
#define WS_CE   20864       // 32768 floats (atomic-accumulated)

// LDS overlay: region1 = max(xs 64x136x2, ys 64x84x4) = 21504 B
//              region2 = max(a0s 80x136x2=21760, mpart 32x80x4=10240) = 21760 B
#define R1SZ 21504
#define LDS_TOTAL (R1SZ + 21760)

__device__ __forceinline__ float leaky(float x) { return x >= 0.f ? x : SLOPE_C * x; }

__device__ __forceinline__ unsigned short f2bf(float f) {   // RNE f32->bf16
    unsigned int u = __float_as_uint(f);
    u += 0x7fffu + ((u >> 16) & 1u);
    return (unsigned short)(u >> 16);
}

// A0bf[c][n] (bf16, c-major), c = t*10+o:  sum_d aw[t,n,d] * W0[o,d]
__global__ void prep_kernel(const float* __restrict__ aw, const float* __restrict__ W0,
                            unsigned short* __restrict__ a0bf) {
    int idx = blockIdx.x * blockDim.x + threadIdx.x;   // c*128 + n
    if (idx >= CDIM * FDIM) return;
    int c = idx >> 7, n = idx & 127;
    int t = c / HDIM, o = c - t * HDIM;
    const float* a = aw + ((size_t)t * FDIM + n) * DDIM;
    const float* w = W0 + o * DDIM;
    float s = 0.f;
#pragma unroll
    for (int d = 0; d < DDIM; ++d) s += a[d] * w[d];
    a0bf[idx] = f2bf(s);
}

// Fused: layer0 GEMM (bf16 MFMA 16x16x32) + W1..W3 chain + head/CE + mean partials.
// Block 256 thr = 4 waves; tile 64 b x 80 c (8 t's). Grid 2048 = 512 bchunk x 4 cchunk.
__global__ __launch_bounds__(256) void gemm0_fused(
    const float* __restrict__ X, const unsigned short* __restrict__ a0bf,
    const float* __restrict__ W1, const float* __restrict__ W2,
    const float* __restrict__ W3, const float* __restrict__ Wh,
    const float* __restrict__ bh,
    float* __restrict__ rep, float* __restrict__ ce_acc,
    float* __restrict__ mean_acc)
{
    __shared__ __align__(16) char ldsbuf[LDS_TOTAL];
    unsigned short (*xs)[136]  = (unsigned short (*)[136])ldsbuf;            // region1
    float          (*ys)[84]   = (float (*)[84])ldsbuf;                      // region1 (after frag load)
    unsigned short (*a0s)[136] = (unsigned short (*)[136])(ldsbuf + R1SZ);   // region2
    float          (*mpart)[80]= (float (*)[80])(ldsbuf + R1SZ);             // region2 (after MFMA)

    int tid = threadIdx.x;
    int bchunk = blockIdx.x >> 2, cchunk = blockIdx.x & 3;
    int b0 = bchunk * 64, c0 = cchunk * 80;

    // ---- stage X tile (f32 -> bf16), coalesced float4 ----
#pragma unroll
    for (int k = 0; k < 8; ++k) {
        int idx = tid + k * 256;             // 2048 float4 = 64 rows x 32
        int row = idx >> 5, col4 = idx & 31;
        float4 v = reinterpret_cast<const float4*>(X + (size_t)(b0 + row) * FDIM)[col4];
        uint2 pk;
        pk.x = (unsigned)f2bf(v.x) | ((unsigned)f2bf(v.y) << 16);
        pk.y = (unsigned)f2bf(v.z) | ((unsigned)f2bf(v.w) << 16);
        *reinterpret_cast<uint2*>(&xs[row][col4 * 4]) = pk;
    }
    // ---- stage A0 tile, coalesced uint4 ----
#pragma unroll
    for (int k = 0; k < 5; ++k) {
        int idx = tid + k * 256;             // 1280 uint4 = 80 rows x 16
        int row = idx >> 4, j = idx & 15;
        uint4 v = reinterpret_cast<const uint4*>(a0bf + (size_t)(c0 + row) * FDIM)[j];
        *reinterpret_cast<uint4*>(&a0s[row][j * 8]) = v;
    }
    __syncthreads();

    int lane = tid & 63, w = tid >> 6;
    int r16 = lane & 15, g = lane >> 4;
    // A-frags: lane holds X[w*16 + r16, k], k = s*32 + g*8 + [0..8)
    bf16x8 af[4];
#pragma unroll
    for (int s = 0; s < 4; ++s)
        af[s] = *reinterpret_cast<const bf16x8*>(&xs[w * 16 + r16][s * 32 + g * 8]);
    __syncthreads();   // all xs reads done before ys overwrites region1

#pragma unroll
    for (int ct = 0; ct < 5; ++ct) {
        f32x4 acc = {0.f, 0.f, 0.f, 0.f};
#pragma unroll
        for (int s = 0; s < 4; ++s) {
            bf16x8 bfrag = *reinterpret_cast<const bf16x8*>(&a0s[ct * 16 + r16][s * 32 + g * 8]);
            acc = __builtin_amdgcn_mfma_f32_16x16x32_bf16(af[s], bfrag, acc, 0, 0, 0);
        }
        // D layout: row = g*4 + r, col = r16
#pragma unroll
        for (int r = 0; r < 4; ++r)
            ys[w * 16 + g * 4 + r][ct * 16 + r16] = acc[r];
    }
    __syncthreads();   // ys complete; a0s dead -> mpart may reuse region2

    // ---- epilogue: 2 (b,t) pairs per thread; pair = tid + p*256 ----
    // bl = pair>>3 (0..63), t8 = pair&7 (same t8 for both pairs of a thread)
    int t8 = tid & 7;
    int t  = cchunk * 8 + t8;
    float mgg[HDIM];
#pragma unroll
    for (int o = 0; o < HDIM; ++o) mgg[o] = 0.f;

#pragma unroll
    for (int p = 0; p < 2; ++p) {
        int bl = (tid >> 3) + p * 32;
        float* yrow = &ys[bl][t8 * HDIM];
        float h[HDIM], lh[HDIM], gg[HDIM];
#pragma unroll
        for (int q = 0; q < 5; ++q) {
            float2 v = reinterpret_cast<const float2*>(yrow)[q];
            h[2 * q] = v.x; h[2 * q + 1] = v.y;
        }
#pragma unroll
        for (int o = 0; o < HDIM; ++o) lh[o] = leaky(h[o]);
#pragma unroll
        for (int o = 0; o < HDIM; ++o) { float s = 0.f;
#pragma unroll
            for (int i = 0; i < HDIM; ++i) s += W1[o * HDIM + i] * lh[i]; gg[o] = s; }
#pragma unroll
        for (int o = 0; o < HDIM; ++o) lh[o] = leaky(gg[o]);
#pragma unroll
        for (int o = 0; o < HDIM; ++o) { float s = 0.f;
#pragma unroll
            for (int i = 0; i < HDIM; ++i) s += W2[o * HDIM + i] * lh[i]; h[o] = s; }
#pragma unroll
        for (int o = 0; o < HDIM; ++o) lh[o] = leaky(h[o]);
#pragma unroll
        for (int o = 0; o < HDIM; ++o) { float s = 0.f;
#pragma unroll
            for (int i = 0; i < HDIM; ++i) s += W3[o * HDIM + i] * lh[i]; gg[o] = s; }

        // write rep back into ys (own slot; coalesced global copy later)
#pragma unroll
        for (int q = 0; q < 5; ++q) {
            float2 v; v.x = gg[2 * q]; v.y = gg[2 * q + 1];
            reinterpret_cast<float2*>(yrow)[q] = v;
        }
#pragma unroll
        for (int o = 0; o < HDIM; ++o) mgg[o] += gg[o];

        // head + CE(class=t), online logsumexp (no p[32] array -> no spills)
#pragma unroll
        for (int o = 0; o < HDIM; ++o) lh[o] = leaky(gg[o]);
        float m = -1e30f, se = 0.f, pt = 0.f;
#pragma unroll
        for (int o = 0; o < TDIM; ++o) {
            float s = bh[o];
#pragma unroll
            for (int i = 0; i < HDIM; ++i) s += Wh[o * HDIM + i] * lh[i];
            pt = (o == t) ? s : pt;
            float nm = fmaxf(m, s);
            se = se * __expf(m - nm) + __expf(s - nm);
            m = nm;
        }
        float ce = m + __logf(se) - pt;
        // reduce ce over the 8 t8-lanes (masks 1,2,4 stay within the 8-lane group)
        ce += __shfl_xor(ce, 1, 64);
        ce += __shfl_xor(ce, 2, 64);
        ce += __shfl_xor(ce, 4, 64);
        if (t8 == 0) atomicAdd(&ce_acc[b0 + bl], ce);
    }

    // mean partials: row = tid>>3 (b-pair group), cols t8*10..+10
#pragma unroll
    for (int o = 0; o < HDIM; ++o) mpart[tid >> 3][t8 * HDIM + o] = mgg[o];
    __syncthreads();

    // coalesced rep copy-out: 64 rows x 80 f32 = 1280 float4
#pragma unroll
    for (int k = 0; k < 5; ++k) {
        int idx = tid + k * 256;
        int row = idx / 20, j = idx - row * 20;
        float4 v = *reinterpret_cast<const float4*>(&ys[row][j * 4]);
        reinterpret_cast<float4*>(rep + (size_t)(b0 + row) * CDIM + c0)[j] = v;
    }
    // mean reduce: 80 columns, 32 rows each -> one atomic per column
    if (tid < 80) {
        float s = 0.f;
#pragma unroll
        for (int r = 0; r < 32; ++r) s += mpart[r][tid];
        atomicAdd(&mean_acc[c0 + tid], s);
    }
}

// triplet-center hinge via ||r||^2 - 2 r.m + ||m||^2; 1 thread per (b,t)
__global__ __launch_bounds__(256) void tc_kernel(const float* __restrict__ rep,
    const float* __restrict__ mean_acc, float* __restrict__ tc_sum)
{
    __shared__ float mm[TDIM * HDIM];
    __shared__ float msq[TDIM];
    __shared__ float wpart[4];
    int tid = threadIdx.x;
    for (int i = tid; i < TDIM * HDIM; i += 256) mm[i] = mean_acc[i] * (1.f / BTOT);
    __syncthreads();
    if (tid < TDIM) {
        float s = 0.f;
#pragma unroll
        for (int h = 0; h < HDIM; ++h) { float v = mm[tid * HDIM + h]; s += v * v; }
        msq[tid] = s;
    }
    __syncthreads();
    size_t idx = (size_t)blockIdx.x * 256 + tid;   // b*32 + t
    int t = (int)(idx & 31);
    const float* r = rep + idx * HDIM;
    float rv[HDIM];
    float rsq = 0.f;
#pragma unroll
    for (int h = 0; h < HDIM; ++h) { rv[h] = r[h]; rsq += rv[h] * rv[h]; }
    float pos = 0.f, neg = 1e30f;
#pragma unroll
    for (int c = 0; c < TDIM; ++c) {
        float dot = 0.f;
#pragma unroll
        for (int h = 0; h < HDIM; ++h) dot += rv[h] * mm[c * HDIM + h];
        float s = rsq - 2.f * dot + msq[c];
        if (c == t) pos = s;
        float s2 = (c == t) ? s + OFFSET_C : s;
        neg = fminf(neg, s2);
    }
    float hinge = fmaxf(pos + MARGIN_C - neg, 0.f);
#pragma unroll
    for (int m = 32; m; m >>= 1) hinge += __shfl_xor(hinge, m, 64);
    int lane = tid & 63, wid = tid >> 6;
    if (lane == 0) wpart[wid] = hinge;
    __syncthreads();
    if (tid == 0) atomicAdd(tc_sum, wpart[0] + wpart[1] + wpart[2] + wpart[3]);
}

__global__ void final_kernel(const float* __restrict__ ce_acc,
                             const float* __restrict__ tc_sum, float* __restrict__ loss)
{
    int b = blockIdx.x * blockDim.x + threadIdx.x;
    if (b < BTOT)
        loss[b] = ALPHA_C * (tc_sum[0] * (1.f / ((float)BTOT * TDIM)))
                + ce_acc[b] * (1.f / TDIM);
}

extern "C" void kernel_launch(void* const* d_in, const int* in_sizes, int n_in,
                              void* d_out, int out_size, void* d_ws, size_t ws_size,
                              hipStream_t stream) {
    const float* X  = (const float*)d_in[0];
    const float* aw = (const float*)d_in[1];
    const float* W0 = (const float*)d_in[2];
    const float* W1 = (const float*)d_in[3];
    const float* W2 = (const float*)d_in[4];
    const float* W3 = (const float*)d_in[5];
    const float* Wh = (const float*)d_in[6];
    const float* bh = (const float*)d_in[7];
    float* ws = (float*)d_ws;
    unsigned short* a0bf = (unsigned short*)(ws + WS_A0BF);
    float* mean_acc = ws + WS_MEAN;
    float* tc_sum   = ws + WS_TC;
    float* ce_acc   = ws + WS_CE;
    float* out_rep = (float*)d_out;        // [32768][320]
    float* loss = out_rep + (size_t)BTOT * TDIM * HDIM;

    // zero mean_acc + tc pad + ce_acc (384 + 32768 floats)
    hipMemsetAsync(mean_acc, 0, (384 + BTOT) * sizeof(float), stream);
    prep_kernel<<<(CDIM * FDIM) / 256, 256, 0, stream>>>(aw, W0, a0bf);
    gemm0_fused<<<2048, 256, 0, stream>>>(X, a0bf, W1, W2, W3, Wh, bh,
                                          out_rep, ce_acc, mean_acc);
    tc_kernel<<<(BTOT * TDIM) / 256, 256, 0, stream>>>(out_rep, mean_acc, tc_sum);
    final_kernel<<<BTOT / 256, 256, 0, stream>>>(ce_acc, tc_sum, loss);
}

// Round 6
// 89.348 us; speedup vs baseline: 4.0100x; 1.3855x over previous
//
#include <hip/hip_runtime.h>

typedef __attribute__((ext_vector_type(8))) short bf16x8;
typedef __attribute__((ext_vector_type(4))) float f32x4;

#define BTOT 32768
#define FDIM 128
#define TDIM 32
#define DDIM 16
#define HDIM 10
#define CDIM 320            // T*H
#define ALPHA_C 0.1f
#define MARGIN_C 1.0f
#define SLOPE_C 0.2f
#define OFFSET_C 1.0e6f

// ws float offsets
#define WS_A0BF 0           // 320*128 bf16 = 20480 floats of storage
#define WS_MEAN 20480       // 320 floats
#define WS_TC   20800       // 1 float (pad to 20864)
#define WS_CE   20864       // 32768 floats (atomic-accumulated)

// LDS overlay: region1 = max(xs 64x136x2, ys 64x84x4) = 21504 B
//              region2 = max(a0s 80x136x2=21760, mpart 32x80x4=10240) = 21760 B
#define R1SZ 21504
#define LDS_TOTAL (R1SZ + 21760)

__device__ __forceinline__ float leaky(float x) { return x >= 0.f ? x : SLOPE_C * x; }

__device__ __forceinline__ unsigned short f2bf(float f) {   // RNE f32->bf16
    unsigned int u = __float_as_uint(f);
    u += 0x7fffu + ((u >> 16) & 1u);
    return (unsigned short)(u >> 16);
}

// A0bf[c][n] (bf16, c-major), c = t*10+o:  sum_d aw[t,n,d] * W0[o,d]
__global__ void prep_kernel(const float* __restrict__ aw, const float* __restrict__ W0,
                            unsigned short* __restrict__ a0bf) {
    int idx = blockIdx.x * blockDim.x + threadIdx.x;   // c*128 + n
    if (idx >= CDIM * FDIM) return;
    int c = idx >> 7, n = idx & 127;
    int t = c / HDIM, o = c - t * HDIM;
    const float* a = aw + ((size_t)t * FDIM + n) * DDIM;
    const float* w = W0 + o * DDIM;
    float s = 0.f;
#pragma unroll
    for (int d = 0; d < DDIM; ++d) s += a[d] * w[d];
    a0bf[idx] = f2bf(s);
}

// Fused: layer0 GEMM (bf16 MFMA 16x16x32) + W1..W3 chain + head/CE + mean partials.
// Block 256 thr = 4 waves; tile 64 b x 80 c (8 t's). Grid 2048 = 512 bchunk x 4 cchunk.
__global__ __launch_bounds__(256) void gemm0_fused(
    const float* __restrict__ X, const unsigned short* __restrict__ a0bf,
    const float* __restrict__ W1, const float* __restrict__ W2,
    const float* __restrict__ W3, const float* __restrict__ Wh,
    const float* __restrict__ bh,
    float* __restrict__ rep, float* __restrict__ ce_acc,
    float* __restrict__ mean_acc)
{
    __shared__ __align__(16) char ldsbuf[LDS_TOTAL];
    unsigned short (*xs)[136]  = (unsigned short (*)[136])ldsbuf;            // region1
    float          (*ys)[84]   = (float (*)[84])ldsbuf;                      // region1 (after frag load)
    unsigned short (*a0s)[136] = (unsigned short (*)[136])(ldsbuf + R1SZ);   // region2
    float          (*mpart)[80]= (float (*)[80])(ldsbuf + R1SZ);             // region2 (after MFMA)

    int tid = threadIdx.x;
    int bchunk = blockIdx.x >> 2, cchunk = blockIdx.x & 3;
    int b0 = bchunk * 64, c0 = cchunk * 80;

    // ---- stage X tile (f32 -> bf16), coalesced float4 ----
#pragma unroll
    for (int k = 0; k < 8; ++k) {
        int idx = tid + k * 256;             // 2048 float4 = 64 rows x 32
        int row = idx >> 5, col4 = idx & 31;
        float4 v = reinterpret_cast<const float4*>(X + (size_t)(b0 + row) * FDIM)[col4];
        uint2 pk;
        pk.x = (unsigned)f2bf(v.x) | ((unsigned)f2bf(v.y) << 16);
        pk.y = (unsigned)f2bf(v.z) | ((unsigned)f2bf(v.w) << 16);
        *reinterpret_cast<uint2*>(&xs[row][col4 * 4]) = pk;
    }
    // ---- stage A0 tile, coalesced uint4 ----
#pragma unroll
    for (int k = 0; k < 5; ++k) {
        int idx = tid + k * 256;             // 1280 uint4 = 80 rows x 16
        int row = idx >> 4, j = idx & 15;
        uint4 v = reinterpret_cast<const uint4*>(a0bf + (size_t)(c0 + row) * FDIM)[j];
        *reinterpret_cast<uint4*>(&a0s[row][j * 8]) = v;
    }
    __syncthreads();

    int lane = tid & 63, w = tid >> 6;
    int r16 = lane & 15, g = lane >> 4;
    // A-frags: lane holds X[w*16 + r16, k], k = s*32 + g*8 + [0..8)
    bf16x8 af[4];
#pragma unroll
    for (int s = 0; s < 4; ++s)
        af[s] = *reinterpret_cast<const bf16x8*>(&xs[w * 16 + r16][s * 32 + g * 8]);
    __syncthreads();   // all xs reads done before ys overwrites region1

#pragma unroll
    for (int ct = 0; ct < 5; ++ct) {
        f32x4 acc = {0.f, 0.f, 0.f, 0.f};
#pragma unroll
        for (int s = 0; s < 4; ++s) {
            bf16x8 bfrag = *reinterpret_cast<const bf16x8*>(&a0s[ct * 16 + r16][s * 32 + g * 8]);
            acc = __builtin_amdgcn_mfma_f32_16x16x32_bf16(af[s], bfrag, acc, 0, 0, 0);
        }
        // D layout: row = g*4 + r, col = r16
#pragma unroll
        for (int r = 0; r < 4; ++r)
            ys[w * 16 + g * 4 + r][ct * 16 + r16] = acc[r];
    }
    __syncthreads();   // ys complete; a0s dead -> mpart may reuse region2

    // ---- epilogue: 2 (b,t) pairs per thread; pair = tid + p*256 ----
    int t8 = tid & 7;
    int t  = cchunk * 8 + t8;
    float mgg[HDIM];
#pragma unroll
    for (int o = 0; o < HDIM; ++o) mgg[o] = 0.f;

#pragma unroll
    for (int p = 0; p < 2; ++p) {
        int bl = (tid >> 3) + p * 32;
        float* yrow = &ys[bl][t8 * HDIM];
        float h[HDIM], lh[HDIM], gg[HDIM];
#pragma unroll
        for (int q = 0; q < 5; ++q) {
            float2 v = reinterpret_cast<const float2*>(yrow)[q];
            h[2 * q] = v.x; h[2 * q + 1] = v.y;
        }
#pragma unroll
        for (int o = 0; o < HDIM; ++o) lh[o] = leaky(h[o]);
#pragma unroll
        for (int o = 0; o < HDIM; ++o) { float s = 0.f;
#pragma unroll
            for (int i = 0; i < HDIM; ++i) s += W1[o * HDIM + i] * lh[i]; gg[o] = s; }
#pragma unroll
        for (int o = 0; o < HDIM; ++o) lh[o] = leaky(gg[o]);
#pragma unroll
        for (int o = 0; o < HDIM; ++o) { float s = 0.f;
#pragma unroll
            for (int i = 0; i < HDIM; ++i) s += W2[o * HDIM + i] * lh[i]; h[o] = s; }
#pragma unroll
        for (int o = 0; o < HDIM; ++o) lh[o] = leaky(h[o]);
#pragma unroll
        for (int o = 0; o < HDIM; ++o) { float s = 0.f;
#pragma unroll
            for (int i = 0; i < HDIM; ++i) s += W3[o * HDIM + i] * lh[i]; gg[o] = s; }

        // write rep back into ys (own slot; coalesced global copy later)
#pragma unroll
        for (int q = 0; q < 5; ++q) {
            float2 v; v.x = gg[2 * q]; v.y = gg[2 * q + 1];
            reinterpret_cast<float2*>(yrow)[q] = v;
        }
#pragma unroll
        for (int o = 0; o < HDIM; ++o) mgg[o] += gg[o];

        // head + CE(class=t), online logsumexp (no p[32] array -> no spills)
#pragma unroll
        for (int o = 0; o < HDIM; ++o) lh[o] = leaky(gg[o]);
        float m = -1e30f, se = 0.f, pt = 0.f;
#pragma unroll
        for (int o = 0; o < TDIM; ++o) {
            float s = bh[o];
#pragma unroll
            for (int i = 0; i < HDIM; ++i) s += Wh[o * HDIM + i] * lh[i];
            pt = (o == t) ? s : pt;
            float nm = fmaxf(m, s);
            se = se * __expf(m - nm) + __expf(s - nm);
            m = nm;
        }
        float ce = m + __logf(se) - pt;
        ce += __shfl_xor(ce, 1, 64);
        ce += __shfl_xor(ce, 2, 64);
        ce += __shfl_xor(ce, 4, 64);
        if (t8 == 0) atomicAdd(&ce_acc[b0 + bl], ce);
    }

    // mean partials: row = tid>>3 (b-pair group), cols t8*10..+10
#pragma unroll
    for (int o = 0; o < HDIM; ++o) mpart[tid >> 3][t8 * HDIM + o] = mgg[o];
    __syncthreads();

    // coalesced rep copy-out: 64 rows x 80 f32 = 1280 float4
#pragma unroll
    for (int k = 0; k < 5; ++k) {
        int idx = tid + k * 256;
        int row = idx / 20, j = idx - row * 20;
        float4 v = *reinterpret_cast<const float4*>(&ys[row][j * 4]);
        reinterpret_cast<float4*>(rep + (size_t)(b0 + row) * CDIM + c0)[j] = v;
    }
    // mean reduce: 80 columns, 32 rows each -> one atomic per column
    if (tid < 80) {
        float s = 0.f;
#pragma unroll
        for (int r = 0; r < 32; ++r) s += mpart[r][tid];
        atomicAdd(&mean_acc[c0 + tid], s);
    }
}

// Triplet-center hinge, restructured: block = 32 b's staged in LDS (coalesced),
// thread = (t, 4 b's) -> each mm class load feeds 40 FMAs; 4 independent chains (ILP).
__global__ __launch_bounds__(256) void tc_kernel(const float* __restrict__ rep,
    const float* __restrict__ mean_acc, float* __restrict__ tc_sum)
{
    __shared__ float tile[32][CDIM];     // 40 KB
    __shared__ float mm[CDIM];
    __shared__ float msq[TDIM];
    __shared__ float wpart[4];
    int tid = threadIdx.x;
    int b0 = blockIdx.x * 32;

    for (int i = tid; i < CDIM; i += 256) mm[i] = mean_acc[i] * (1.f / BTOT);
    const float4* src = reinterpret_cast<const float4*>(rep + (size_t)b0 * CDIM);
#pragma unroll
    for (int k = 0; k < 10; ++k) {       // 2560 float4, coalesced
        int idx = tid + k * 256;
        int row = idx / 80, col4 = idx - row * 80;
        *reinterpret_cast<float4*>(&tile[row][col4 * 4]) = src[idx];
    }
    __syncthreads();
    if (tid < TDIM) {
        float s = 0.f;
#pragma unroll
        for (int h = 0; h < HDIM; ++h) { float v = mm[tid * HDIM + h]; s += v * v; }
        msq[tid] = s;
    }
    __syncthreads();

    int t = tid & 31, bg = tid >> 5;     // 8 b-groups x 4 b's
    float rv[4][HDIM], rsq[4];
#pragma unroll
    for (int j = 0; j < 4; ++j) {
        const float* rp = &tile[bg * 4 + j][t * HDIM];
        float s = 0.f;
#pragma unroll
        for (int q = 0; q < 5; ++q) {
            float2 v = reinterpret_cast<const float2*>(rp)[q];
            rv[j][2 * q] = v.x; rv[j][2 * q + 1] = v.y;
            s += v.x * v.x + v.y * v.y;
        }
        rsq[j] = s;
    }
    float pos[4], neg[4];
#pragma unroll
    for (int j = 0; j < 4; ++j) { pos[j] = 0.f; neg[j] = 1e30f; }
#pragma unroll 4
    for (int c = 0; c < TDIM; ++c) {
        float m0[HDIM];
#pragma unroll
        for (int q = 0; q < 5; ++q) {
            float2 v = reinterpret_cast<const float2*>(&mm[c * HDIM])[q];
            m0[2 * q] = v.x; m0[2 * q + 1] = v.y;
        }
        float mq = msq[c];
        bool isT = (c == t);
#pragma unroll
        for (int j = 0; j < 4; ++j) {
            float dot = 0.f;
#pragma unroll
            for (int h = 0; h < HDIM; ++h) dot += rv[j][h] * m0[h];
            float s = rsq[j] - 2.f * dot + mq;
            if (isT) pos[j] = s;
            float s2 = isT ? s + OFFSET_C : s;
            neg[j] = fminf(neg[j], s2);
        }
    }
    float hs = 0.f;
#pragma unroll
    for (int j = 0; j < 4; ++j) hs += fmaxf(pos[j] + MARGIN_C - neg[j], 0.f);
#pragma unroll
    for (int m = 1; m < 64; m <<= 1) hs += __shfl_xor(hs, m, 64);
    int lane = tid & 63, w = tid >> 6;
    if (lane == 0) wpart[w] = hs;
    __syncthreads();
    if (tid == 0) atomicAdd(tc_sum, wpart[0] + wpart[1] + wpart[2] + wpart[3]);
}

__global__ void final_kernel(const float* __restrict__ ce_acc,
                             const float* __restrict__ tc_sum, float* __restrict__ loss)
{
    int b = blockIdx.x * blockDim.x + threadIdx.x;
    if (b < BTOT)
        loss[b] = ALPHA_C * (tc_sum[0] * (1.f / ((float)BTOT * TDIM)))
                + ce_acc[b] * (1.f / TDIM);
}

extern "C" void kernel_launch(void* const* d_in, const int* in_sizes, int n_in,
                              void* d_out, int out_size, void* d_ws, size_t ws_size,
                              hipStream_t stream) {
    const float* X  = (const float*)d_in[0];
    const float* aw = (const float*)d_in[1];
    const float* W0 = (const float*)d_in[2];
    const float* W1 = (const float*)d_in[3];
    const float* W2 = (const float*)d_in[4];
    const float* W3 = (const float*)d_in[5];
    const float* Wh = (const float*)d_in[6];
    const float* bh = (const float*)d_in[7];
    float* ws = (float*)d_ws;
    unsigned short* a0bf = (unsigned short*)(ws + WS_A0BF);
    float* mean_acc = ws + WS_MEAN;
    float* tc_sum   = ws + WS_TC;
    float* ce_acc   = ws + WS_CE;
    float* out_rep = (float*)d_out;        // [32768][320]
    float* loss = out_rep + (size_t)BTOT * TDIM * HDIM;

    hipMemsetAsync(mean_acc, 0, (384 + BTOT) * sizeof(float), stream);
    prep_kernel<<<(CDIM * FDIM) / 256, 256, 0, stream>>>(aw, W0, a0bf);
    gemm0_fused<<<2048, 256, 0, stream>>>(X, a0bf, W1, W2, W3, Wh, bh,
                                          out_rep, ce_acc, mean_acc);
    tc_kernel<<<BTOT / 32, 256, 0, stream>>>(out_rep, mean_acc, tc_sum);
    final_kernel<<<BTOT / 256, 256, 0, stream>>>(ce_acc, tc_sum, loss);
}